// Round 1
// baseline (6239.113 us; speedup 1.0000x reference)
//
#include <hip/hip_runtime.h>
#include <stdint.h>
#include <stddef.h>

#define AS1 __attribute__((address_space(1)))
#define AS3 __attribute__((address_space(3)))

typedef __attribute__((ext_vector_type(4))) float f32x4;
typedef __attribute__((ext_vector_type(8))) short bf16x8;

static __device__ __forceinline__ unsigned short f2b(float x) {
  union { float f; uint32_t u; } c; c.f = x;
  return (unsigned short)((c.u + 0x7FFFu + ((c.u >> 16) & 1u)) >> 16);
}
static __device__ __forceinline__ float b2f_lo(uint32_t u) {
  union { uint32_t u; float f; } c; c.u = u << 16; return c.f;
}
static __device__ __forceinline__ float b2f_hi(uint32_t u) {
  union { uint32_t u; float f; } c; c.u = u & 0xFFFF0000u; return c.f;
}

// ---------------- prep kernels ----------------

__global__ __launch_bounds__(256) void k_cvt_bf16(const float* __restrict__ s,
                                                  unsigned short* __restrict__ d,
                                                  int n4) {
  int i = blockIdx.x * 256 + threadIdx.x;
  int stride = gridDim.x * 256;
  for (; i < n4; i += stride) {
    float4 v = ((const float4*)s)[i];
    ushort4 o;
    o.x = f2b(v.x); o.y = f2b(v.y); o.z = f2b(v.z); o.w = f2b(v.w);
    ((ushort4*)d)[i] = o;
  }
}

// row m = t*16+b  <-  emb[xs[b][t]]  (bf16)
__global__ __launch_bounds__(128) void k_emb_gather(const int* __restrict__ xs,
                                                    const float* __restrict__ emb,
                                                    unsigned short* __restrict__ out) {
  int m = blockIdx.x;
  int tok = xs[(m & 15) * 128 + (m >> 4)];
  float4 v = ((const float4*)(emb + (size_t)tok * 512))[threadIdx.x];
  ushort4 o;
  o.x = f2b(v.x); o.y = f2b(v.y); o.z = f2b(v.z); o.w = f2b(v.w);
  ((ushort4*)(out + (size_t)m * 512))[threadIdx.x] = o;
}

__global__ __launch_bounds__(256) void k_bias(const float* __restrict__ a,
                                              const float* __restrict__ b,
                                              float* __restrict__ o, int n) {
  int i = blockIdx.x * 256 + threadIdx.x;
  if (i < n) o[i] = a[i] + b[i];
}

// ---------------- bf16 GEMM, B^T layout (m97-style) ----------------
// C[M][N] = A[M][K] * Bt[N][K]^T + bias[N]; M,N multiples of 128, K mult of 32.
__global__ __launch_bounds__(256) void k_gemm_bt(const unsigned short* __restrict__ A,
                                                 const unsigned short* __restrict__ Bt,
                                                 const float* __restrict__ bias,
                                                 float* __restrict__ C,
                                                 int M, int N, int K) {
  __shared__ unsigned short As[128 * 32];
  __shared__ unsigned short Bs[128 * 32];
  const int tiles_n = N >> 7;
  const int tm = blockIdx.x / tiles_n;
  const int tn = blockIdx.x % tiles_n;
  const int m0 = tm << 7, n0 = tn << 7;
  const int tid = threadIdx.x;
  const int wave = tid >> 6, lane = tid & 63;
  const int wr = wave >> 1, wc = wave & 1;
  f32x4 acc[4][4] = {};

  const int lo = wave * 2048 + lane * 16;  // linear byte offset in 8KB tile
  for (int k0 = 0; k0 < K; k0 += 32) {
#pragma unroll
    for (int i = 0; i < 2; ++i) {
      int o = lo + i * 1024;
      int row = o >> 6, kb = o & 63;
      __builtin_amdgcn_global_load_lds(
          (const AS1 uint32_t*)((const char*)A + ((size_t)(m0 + row) * K + k0) * 2 + kb),
          (AS3 uint32_t*)((char*)As + wave * 2048 + i * 1024), 16, 0, 0);
    }
#pragma unroll
    for (int i = 0; i < 2; ++i) {
      int o = lo + i * 1024;
      int row = o >> 6, kb = o & 63;
      __builtin_amdgcn_global_load_lds(
          (const AS1 uint32_t*)((const char*)Bt + ((size_t)(n0 + row) * K + k0) * 2 + kb),
          (AS3 uint32_t*)((char*)Bs + wave * 2048 + i * 1024), 16, 0, 0);
    }
    __syncthreads();
    bf16x8 af[4], bfr[4];
    const int lrow = lane & 15;
    const int kb16 = (lane >> 4) * 16;  // byte offset of this lane's k-slice
#pragma unroll
    for (int i = 0; i < 4; ++i)
      af[i] = *(const bf16x8*)((const char*)As + (wr * 64 + i * 16 + lrow) * 64 + kb16);
#pragma unroll
    for (int j = 0; j < 4; ++j)
      bfr[j] = *(const bf16x8*)((const char*)Bs + (wc * 64 + j * 16 + lrow) * 64 + kb16);
#pragma unroll
    for (int i = 0; i < 4; ++i)
#pragma unroll
      for (int j = 0; j < 4; ++j)
        acc[i][j] = __builtin_amdgcn_mfma_f32_16x16x32_bf16(af[i], bfr[j], acc[i][j], 0, 0, 0);
    __syncthreads();
  }
#pragma unroll
  for (int j = 0; j < 4; ++j) {
    int col = n0 + wc * 64 + j * 16 + (lane & 15);
    float bv = bias[col];
#pragma unroll
    for (int i = 0; i < 4; ++i) {
      int r0 = m0 + wr * 64 + i * 16 + (lane >> 4) * 4;
#pragma unroll
      for (int r = 0; r < 4; ++r)
        C[(size_t)(r0 + r) * N + col] = acc[i][j][r] + bv;
    }
  }
}

// ---------------- persistent LSTM ----------------
// 512 WGs = 16 batches x 32 col-groups (16 h-cols each). W_hh slice (64 rows
// x 512) lives in LDS as bf16 (exactly 64KB). Cross-WG h exchange per step via
// hsf32[t] + release/acquire flags. 2 WG/CU -> all co-resident.

static __device__ __forceinline__ int wsw(int lr, int kb) {
  // XOR-swizzled byte address into the 64x512 bf16 LDS tile (rows of 1024B).
  return lr * 1024 + (kb ^ ((((lr & 7) ^ (((kb >> 8) & 3) << 1)) & 7) << 4));
}

__global__ __launch_bounds__(256) void k_lstm(const float* __restrict__ gp,
                                              const float* __restrict__ Whh,
                                              const float* __restrict__ ench,
                                              const float* __restrict__ encc,
                                              float* __restrict__ hsf,
                                              unsigned short* __restrict__ hsb,
                                              unsigned int* __restrict__ flags) {
  __shared__ unsigned short wlds[64 * 512];  // 65536 B
  char* wbase = (char*)wlds;
  const int wg = blockIdx.x;
  const int b = wg >> 5;
  const int g = wg & 31;
  const int tid = threadIdx.x;
  const int w = tid >> 6;
  const int l = tid & 63;
  const int c_loc = l >> 4;          // 0..3
  const int q = (l >> 2) & 3;        // gate (i,f,g,o)
  const int q4 = l & 3;              // k-quarter
  const int col_l = w * 4 + c_loc;   // 0..15  col within group
  const int lr = q * 16 + col_l;     // 0..63  local W row
  const int col = g * 16 + col_l;    // 0..511 h column
  const int R = q * 512 + col;       // global gate/W row

  // Stage W_hh row R, quarter q4, into LDS (bf16, swizzled).
  for (int ii = 0; ii < 16; ++ii) {
    int k = q4 * 128 + ii * 8;
    const float4* s = (const float4*)(Whh + (size_t)R * 512 + k);
    float4 v0 = s[0], v1 = s[1];
    uint4 p;
    p.x = (uint32_t)f2b(v0.x) | ((uint32_t)f2b(v0.y) << 16);
    p.y = (uint32_t)f2b(v0.z) | ((uint32_t)f2b(v0.w) << 16);
    p.z = (uint32_t)f2b(v1.x) | ((uint32_t)f2b(v1.y) << 16);
    p.w = (uint32_t)f2b(v1.z) | ((uint32_t)f2b(v1.w) << 16);
    *(uint4*)(wbase + wsw(lr, k * 2)) = p;
  }
  const bool active = (l & 15) == 0;
  float c_reg = 0.f;
  if (active) c_reg = encc[b * 512 + col];
  __syncthreads();

  for (int t = 0; t < 128; ++t) {
    if (t > 0) {
      if (tid < 32) {
        unsigned int* fp = flags + (((size_t)b * 128 + (t - 1)) << 5) + tid;
        int guard = 0;
        while (__hip_atomic_load(fp, __ATOMIC_ACQUIRE, __HIP_MEMORY_SCOPE_AGENT) == 0u) {
          __builtin_amdgcn_s_sleep(1);
          if (++guard > (1 << 19)) break;  // hang guard (deadlock -> wrong, not hung)
        }
      }
      __syncthreads();
    }
    const float* hsrc = (t == 0) ? (ench + b * 512)
                                 : (hsf + (((size_t)(t - 1) * 16 + b) << 9));
    // partial dot over this lane's k-quarter; fold in gates_pre/4 (exact)
    float acc = gp[(((size_t)t * 16 + b) << 11) + R] * 0.25f;
    const float* hq = hsrc + q4 * 128;
#pragma unroll 8
    for (int ii = 0; ii < 16; ++ii) {
      uint4 wv = *(const uint4*)(wbase + wsw(lr, q4 * 256 + ii * 16));
      float4 h0 = *(const float4*)(hq + ii * 8);
      float4 h1 = *(const float4*)(hq + ii * 8 + 4);
      acc += b2f_lo(wv.x) * h0.x + b2f_hi(wv.x) * h0.y
           + b2f_lo(wv.y) * h0.z + b2f_hi(wv.y) * h0.w
           + b2f_lo(wv.z) * h1.x + b2f_hi(wv.z) * h1.y
           + b2f_lo(wv.w) * h1.z + b2f_hi(wv.w) * h1.w;
    }
    // reduce across the 4 k-quarters (lanes differing in bits 0..1)
    acc += __shfl_xor(acc, 1);
    acc += __shfl_xor(acc, 2);
    // gather the 4 gates of this lane's column from within the wave
    int lb = l & 48;
    float gi = __shfl(acc, lb);
    float gf = __shfl(acc, lb + 4);
    float gg = __shfl(acc, lb + 8);
    float go = __shfl(acc, lb + 12);
    if (active) {
      float iv = 1.f / (1.f + expf(-gi));
      float fv = 1.f / (1.f + expf(-gf));
      float gv = tanhf(gg);
      float ov = 1.f / (1.f + expf(-go));
      c_reg = fv * c_reg + iv * gv;
      float hv = ov * tanhf(c_reg);
      size_t oi = (((size_t)t * 16 + b) << 9) + col;
      hsf[oi] = hv;
      hsb[oi] = f2b(hv);
      __threadfence();
    }
    __syncthreads();
    if (tid == 0)
      __hip_atomic_store(flags + (((size_t)b * 128 + t) << 5) + g, 1u,
                         __ATOMIC_RELEASE, __HIP_MEMORY_SCOPE_AGENT);
  }
}

// ---------------- launch ----------------

extern "C" void kernel_launch(void* const* d_in, const int* in_sizes, int n_in,
                              void* d_out, int out_size, void* d_ws, size_t ws_size,
                              hipStream_t stream) {
  (void)in_sizes; (void)n_in; (void)out_size; (void)ws_size;
  const int* xs = (const int*)d_in[0];
  // d_in[1] = xs_len (unused by reference)
  const float* ench = (const float*)d_in[2];
  const float* encc = (const float*)d_in[3];
  const float* emb  = (const float*)d_in[4];
  const float* Wih  = (const float*)d_in[5];
  const float* Whh  = (const float*)d_in[6];
  const float* bih  = (const float*)d_in[7];
  const float* bhh  = (const float*)d_in[8];
  const float* Wout = (const float*)d_in[9];
  const float* bout = (const float*)d_in[10];
  float* out = (float*)d_out;

  char* ws = (char*)d_ws;
  size_t off = 0;
  auto take = [&](size_t bytes) {
    char* p = ws + off;
    off += (bytes + 255) & ~(size_t)255;
    return p;
  };
  float* gates_pre      = (float*)take(2048ull * 2048 * 4);   // [T*B][4H]
  float* hsf            = (float*)take(2048ull * 512 * 4);    // h per step, f32
  unsigned short* hsb   = (unsigned short*)take(2048ull * 512 * 2);  // h, bf16
  unsigned short* aemb  = (unsigned short*)take(2048ull * 512 * 2);  // emb rows bf16
  unsigned short* wih_b = (unsigned short*)take(2048ull * 512 * 2);
  unsigned short* wout_b= (unsigned short*)take(32000ull * 512 * 2);
  float* bias1          = (float*)take(2048 * 4);
  unsigned int* flags   = (unsigned int*)take(16ull * 128 * 32 * 4);

  k_cvt_bf16<<<1024, 256, 0, stream>>>(Wih, wih_b, 2048 * 512 / 4);
  k_cvt_bf16<<<2048, 256, 0, stream>>>(Wout, wout_b, 32000 * 512 / 4);
  k_emb_gather<<<2048, 128, 0, stream>>>(xs, emb, aemb);
  k_bias<<<8, 256, 0, stream>>>(bih, bhh, bias1, 2048);

  // gates_pre = aemb @ W_ih^T + (b_ih + b_hh)
  k_gemm_bt<<<256, 256, 0, stream>>>(aemb, wih_b, bias1, gates_pre, 2048, 2048, 512);

  hipMemsetAsync(flags, 0, 16ull * 128 * 32 * 4, stream);
  k_lstm<<<512, 256, 0, stream>>>(gates_pre, Whh, ench, encc, hsf, hsb, flags);

  // logits = hs @ W_out^T + b_out
  k_gemm_bt<<<4000, 256, 0, stream>>>(hsb, wout_b, bout, out, 2048, 32000, 512);
}

// Round 2
// 666.324 us; speedup vs baseline: 9.3635x; 9.3635x over previous
//
#include <hip/hip_runtime.h>
#include <stdint.h>
#include <stddef.h>

#define AS1 __attribute__((address_space(1)))
#define AS3 __attribute__((address_space(3)))

typedef __attribute__((ext_vector_type(4))) float f32x4;
typedef __attribute__((ext_vector_type(8))) short bf16x8;

static __device__ __forceinline__ unsigned short f2b(float x) {
  union { float f; uint32_t u; } c; c.f = x;
  return (unsigned short)((c.u + 0x7FFFu + ((c.u >> 16) & 1u)) >> 16);
}
static __device__ __forceinline__ float b2f_lo(uint32_t u) {
  union { uint32_t u; float f; } c; c.u = u << 16; return c.f;
}
static __device__ __forceinline__ float b2f_hi(uint32_t u) {
  union { uint32_t u; float f; } c; c.u = u & 0xFFFF0000u; return c.f;
}

// ---------------- prep kernels ----------------

__global__ __launch_bounds__(256) void k_cvt_bf16(const float* __restrict__ s,
                                                  unsigned short* __restrict__ d,
                                                  int n4) {
  int i = blockIdx.x * 256 + threadIdx.x;
  int stride = gridDim.x * 256;
  for (; i < n4; i += stride) {
    float4 v = ((const float4*)s)[i];
    ushort4 o;
    o.x = f2b(v.x); o.y = f2b(v.y); o.z = f2b(v.z); o.w = f2b(v.w);
    ((ushort4*)d)[i] = o;
  }
}

// row m = t*16+b  <-  emb[xs[b][t]]  (bf16)
__global__ __launch_bounds__(128) void k_emb_gather(const int* __restrict__ xs,
                                                    const float* __restrict__ emb,
                                                    unsigned short* __restrict__ out) {
  int m = blockIdx.x;
  int tok = xs[(m & 15) * 128 + (m >> 4)];
  float4 v = ((const float4*)(emb + (size_t)tok * 512))[threadIdx.x];
  ushort4 o;
  o.x = f2b(v.x); o.y = f2b(v.y); o.z = f2b(v.z); o.w = f2b(v.w);
  ((ushort4*)(out + (size_t)m * 512))[threadIdx.x] = o;
}

__global__ __launch_bounds__(256) void k_bias(const float* __restrict__ a,
                                              const float* __restrict__ b,
                                              float* __restrict__ o, int n) {
  int i = blockIdx.x * 256 + threadIdx.x;
  if (i < n) o[i] = a[i] + b[i];
}

// ---------------- bf16 GEMM, B^T layout (m97-style) ----------------
// C[M][N] = A[M][K] * Bt[N][K]^T + bias[N]; M,N multiples of 128, K mult of 32.
__global__ __launch_bounds__(256) void k_gemm_bt(const unsigned short* __restrict__ A,
                                                 const unsigned short* __restrict__ Bt,
                                                 const float* __restrict__ bias,
                                                 float* __restrict__ C,
                                                 int M, int N, int K) {
  __shared__ unsigned short As[128 * 32];
  __shared__ unsigned short Bs[128 * 32];
  const int tiles_n = N >> 7;
  const int tm = blockIdx.x / tiles_n;
  const int tn = blockIdx.x % tiles_n;
  const int m0 = tm << 7, n0 = tn << 7;
  const int tid = threadIdx.x;
  const int wave = tid >> 6, lane = tid & 63;
  const int wr = wave >> 1, wc = wave & 1;
  f32x4 acc[4][4] = {};

  const int lo = wave * 2048 + lane * 16;  // linear byte offset in 8KB tile
  for (int k0 = 0; k0 < K; k0 += 32) {
#pragma unroll
    for (int i = 0; i < 2; ++i) {
      int o = lo + i * 1024;
      int row = o >> 6, kb = o & 63;
      __builtin_amdgcn_global_load_lds(
          (const AS1 uint32_t*)((const char*)A + ((size_t)(m0 + row) * K + k0) * 2 + kb),
          (AS3 uint32_t*)((char*)As + wave * 2048 + i * 1024), 16, 0, 0);
    }
#pragma unroll
    for (int i = 0; i < 2; ++i) {
      int o = lo + i * 1024;
      int row = o >> 6, kb = o & 63;
      __builtin_amdgcn_global_load_lds(
          (const AS1 uint32_t*)((const char*)Bt + ((size_t)(n0 + row) * K + k0) * 2 + kb),
          (AS3 uint32_t*)((char*)Bs + wave * 2048 + i * 1024), 16, 0, 0);
    }
    __syncthreads();
    bf16x8 af[4], bfr[4];
    const int lrow = lane & 15;
    const int kb16 = (lane >> 4) * 16;  // byte offset of this lane's k-slice
#pragma unroll
    for (int i = 0; i < 4; ++i)
      af[i] = *(const bf16x8*)((const char*)As + (wr * 64 + i * 16 + lrow) * 64 + kb16);
#pragma unroll
    for (int j = 0; j < 4; ++j)
      bfr[j] = *(const bf16x8*)((const char*)Bs + (wc * 64 + j * 16 + lrow) * 64 + kb16);
#pragma unroll
    for (int i = 0; i < 4; ++i)
#pragma unroll
      for (int j = 0; j < 4; ++j)
        acc[i][j] = __builtin_amdgcn_mfma_f32_16x16x32_bf16(af[i], bfr[j], acc[i][j], 0, 0, 0);
    __syncthreads();
  }
#pragma unroll
  for (int j = 0; j < 4; ++j) {
    int col = n0 + wc * 64 + j * 16 + (lane & 15);
    float bv = bias[col];
#pragma unroll
    for (int i = 0; i < 4; ++i) {
      int r0 = m0 + wr * 64 + i * 16 + (lane >> 4) * 4;
#pragma unroll
      for (int r = 0; r < 4; ++r)
        C[(size_t)(r0 + r) * N + col] = acc[i][j][r] + bv;
    }
  }
}

// ---------------- persistent LSTM (fence-free, sentinel-based) ----------------
// 256 WGs = 16 batches x 16 col-groups (32 h-cols each). W_hh slice (128 rows
// x 512) in LDS as bf16 (128KB) -> 1 WG/CU, all 256 co-resident (LDS-forced).
// Cross-WG h exchange: h values ARE the flags. hsf pre-memset to 0xFFFFFFFF
// (NaN sentinel, unreachable for o*tanh(c)). Producers store h with RELAXED
// agent-scope atomics (sc1 -> IF$, no wbl2); consumers spin with RELAXED
// agent-scope 8B atomic loads (no invalidates). Zero fences in the hot loop.

static __device__ __forceinline__ int wsw(int lr, int kb) {
  // XOR-swizzled byte address into 128-row x 1024B LDS tile.
  return lr * 1024 + (kb ^ ((((lr & 7) ^ (((kb >> 8) & 3) << 1)) & 7) << 4));
}

__global__ __launch_bounds__(512) void k_lstm(const float* __restrict__ gp,
                                              const float* __restrict__ Whh,
                                              const float* __restrict__ ench,
                                              const float* __restrict__ encc,
                                              float* __restrict__ hsf,
                                              unsigned short* __restrict__ hsb) {
  __shared__ unsigned short wlds[128 * 512];  // 131072 B
  __shared__ float hb[512];                   // staged h_{t-1} (f32)
  char* wbase = (char*)wlds;
  const int b = blockIdx.x >> 4;
  const int g = blockIdx.x & 15;
  const int c0 = g * 32;
  const int tid = threadIdx.x;
  const int w = tid >> 6, l = tid & 63;

  // ---- stage W_hh slice into LDS (bf16, swizzled) ----
  {
    const int r = tid >> 2;   // local row 0..127  (= q*32 + c)
    const int p = tid & 3;    // k-quarter (128 weights)
    const int R = (r >> 5) * 512 + c0 + (r & 31);
    const float4* src = (const float4*)(Whh + (size_t)R * 512 + p * 128);
#pragma unroll 4
    for (int ii = 0; ii < 16; ++ii) {
      float4 v0 = src[2 * ii], v1 = src[2 * ii + 1];
      uint4 pk;
      pk.x = (uint32_t)f2b(v0.x) | ((uint32_t)f2b(v0.y) << 16);
      pk.y = (uint32_t)f2b(v0.z) | ((uint32_t)f2b(v0.w) << 16);
      pk.z = (uint32_t)f2b(v1.x) | ((uint32_t)f2b(v1.y) << 16);
      pk.w = (uint32_t)f2b(v1.z) | ((uint32_t)f2b(v1.w) << 16);
      *(uint4*)(wbase + wsw(r, p * 256 + ii * 16)) = pk;
    }
  }

  // ---- per-thread roles for the gate dot ----
  const int p = l & 3;                 // k-quarter
  const int q = (l >> 2) & 3;         // gate (i,f,g,o)
  const int cl = w * 4 + (l >> 4);    // col within group 0..31
  const int col = c0 + cl;            // 0..511
  const int lr = q * 32 + cl;         // local W row
  const int R = q * 512 + col;        // global gate row
  const bool active = (l & 15) == 0;  // 32 h-producers per WG
  float c_reg = active ? encc[b * 512 + col] : 0.f;

  __syncthreads();
  // stage h_{-1} = enc_h (plain loads; input buffer, coherent at launch)
  if (tid < 256) {
    float2 hv = ((const float2*)(ench + b * 512))[tid];
    hb[2 * tid] = hv.x; hb[2 * tid + 1] = hv.y;
  }
  __syncthreads();

  float gpv = 0.25f * gp[((size_t)b << 11) + R];  // t=0 pre-gates (prefetched)

  for (int t = 0; t < 128; ++t) {
    float acc = gpv;
    const float4* hq = (const float4*)(hb + p * 128);
#pragma unroll
    for (int ii = 0; ii < 16; ++ii) {
      uint4 wv = *(const uint4*)(wbase + wsw(lr, p * 256 + ii * 16));
      float4 h0 = hq[2 * ii];
      float4 h1 = hq[2 * ii + 1];
      acc += b2f_lo(wv.x) * h0.x + b2f_hi(wv.x) * h0.y
           + b2f_lo(wv.y) * h0.z + b2f_hi(wv.y) * h0.w
           + b2f_lo(wv.z) * h1.x + b2f_hi(wv.z) * h1.y
           + b2f_lo(wv.w) * h1.z + b2f_hi(wv.w) * h1.w;
    }
    // reduce across the 4 k-quarters (lane bits 0..1)
    acc += __shfl_xor(acc, 1);
    acc += __shfl_xor(acc, 2);
    // gather the 4 gates of this lane-group's column
    int lb = l & 48;
    float gi = __shfl(acc, lb);
    float gf = __shfl(acc, lb + 4);
    float gg = __shfl(acc, lb + 8);
    float go = __shfl(acc, lb + 12);
    if (active) {
      float iv = 1.f / (1.f + expf(-gi));
      float fv = 1.f / (1.f + expf(-gf));
      float gv = tanhf(gg);
      float ov = 1.f / (1.f + expf(-go));
      c_reg = fv * c_reg + iv * gv;
      float hv = ov * tanhf(c_reg);
      size_t oi = (((size_t)t * 16 + b) << 9) + col;
      union { float f; uint32_t u; } cvt; cvt.f = hv;
      __hip_atomic_store((uint32_t*)hsf + oi, cvt.u,
                         __ATOMIC_RELAXED, __HIP_MEMORY_SCOPE_AGENT);
      hsb[oi] = f2b(hv);
    }
    if (t < 127) {
      // prefetch next step's pre-gates while we wait
      gpv = 0.25f * gp[(((size_t)(t + 1) * 16 + b) << 11) + R];
      __syncthreads();  // hb free for rewrite
      if (tid < 256) {
        const uint64_t* src =
            (const uint64_t*)(hsf + (((size_t)t * 16 + b) << 9)) + tid;
        uint64_t v;
        int guard = 0;
        for (;;) {
          v = __hip_atomic_load(src, __ATOMIC_RELAXED, __HIP_MEMORY_SCOPE_AGENT);
          if ((uint32_t)v != 0xFFFFFFFFu && (uint32_t)(v >> 32) != 0xFFFFFFFFu)
            break;
          __builtin_amdgcn_s_sleep(1);
          if (++guard > (1 << 18)) break;  // hang guard: wrong, not hung
        }
        union { uint64_t u; float f[2]; } cv; cv.u = v;
        hb[2 * tid] = cv.f[0]; hb[2 * tid + 1] = cv.f[1];
      }
      __syncthreads();
    }
  }
}

// ---------------- launch ----------------

extern "C" void kernel_launch(void* const* d_in, const int* in_sizes, int n_in,
                              void* d_out, int out_size, void* d_ws, size_t ws_size,
                              hipStream_t stream) {
  (void)in_sizes; (void)n_in; (void)out_size; (void)ws_size;
  const int* xs = (const int*)d_in[0];
  // d_in[1] = xs_len (unused by reference)
  const float* ench = (const float*)d_in[2];
  const float* encc = (const float*)d_in[3];
  const float* emb  = (const float*)d_in[4];
  const float* Wih  = (const float*)d_in[5];
  const float* Whh  = (const float*)d_in[6];
  const float* bih  = (const float*)d_in[7];
  const float* bhh  = (const float*)d_in[8];
  const float* Wout = (const float*)d_in[9];
  const float* bout = (const float*)d_in[10];
  float* out = (float*)d_out;

  char* ws = (char*)d_ws;
  size_t off = 0;
  auto take = [&](size_t bytes) {
    char* p = ws + off;
    off += (bytes + 255) & ~(size_t)255;
    return p;
  };
  float* gates_pre      = (float*)take(2048ull * 2048 * 4);   // [T*B][4H]
  float* hsf            = (float*)take(2048ull * 512 * 4);    // h per step, f32
  unsigned short* hsb   = (unsigned short*)take(2048ull * 512 * 2);  // h, bf16
  unsigned short* aemb  = (unsigned short*)take(2048ull * 512 * 2);  // emb rows bf16
  unsigned short* wih_b = (unsigned short*)take(2048ull * 512 * 2);
  unsigned short* wout_b= (unsigned short*)take(32000ull * 512 * 2);
  float* bias1          = (float*)take(2048 * 4);

  k_cvt_bf16<<<1024, 256, 0, stream>>>(Wih, wih_b, 2048 * 512 / 4);
  k_cvt_bf16<<<2048, 256, 0, stream>>>(Wout, wout_b, 32000 * 512 / 4);
  k_emb_gather<<<2048, 128, 0, stream>>>(xs, emb, aemb);
  k_bias<<<8, 256, 0, stream>>>(bih, bhh, bias1, 2048);

  // gates_pre = aemb @ W_ih^T + (b_ih + b_hh)
  k_gemm_bt<<<256, 256, 0, stream>>>(aemb, wih_b, bias1, gates_pre, 2048, 2048, 512);

  // sentinel-fill h buffer (0xFFFFFFFF = NaN, unreachable for o*tanh(c))
  hipMemsetAsync(hsf, 0xFF, 2048ull * 512 * 4, stream);
  k_lstm<<<256, 512, 0, stream>>>(gates_pre, Whh, ench, encc, hsf, hsb);

  // logits = hs @ W_out^T + b_out
  k_gemm_bt<<<4000, 256, 0, stream>>>(hsb, wout_b, bout, out, 2048, 32000, 512);
}

// Round 3
// 602.400 us; speedup vs baseline: 10.3571x; 1.1061x over previous
//
#include <hip/hip_runtime.h>
#include <stdint.h>
#include <stddef.h>

#define AS1 __attribute__((address_space(1)))
#define AS3 __attribute__((address_space(3)))

typedef __attribute__((ext_vector_type(4))) float f32x4;
typedef __attribute__((ext_vector_type(8))) short bf16x8;

static __device__ __forceinline__ unsigned short f2b(float x) {
  union { float f; uint32_t u; } c; c.f = x;
  return (unsigned short)((c.u + 0x7FFFu + ((c.u >> 16) & 1u)) >> 16);
}
static __device__ __forceinline__ float fsig(float x) {
  return __builtin_amdgcn_rcpf(1.f + __expf(-x));
}
static __device__ __forceinline__ float ftanh(float x) {
  return 1.f - 2.f * __builtin_amdgcn_rcpf(__expf(2.f * x) + 1.f);
}

// ---------------- prep kernels ----------------

__global__ __launch_bounds__(256) void k_cvt_bf16(const float* __restrict__ s,
                                                  unsigned short* __restrict__ d,
                                                  int n4) {
  int i = blockIdx.x * 256 + threadIdx.x;
  int stride = gridDim.x * 256;
  for (; i < n4; i += stride) {
    float4 v = ((const float4*)s)[i];
    ushort4 o;
    o.x = f2b(v.x); o.y = f2b(v.y); o.z = f2b(v.z); o.w = f2b(v.w);
    ((ushort4*)d)[i] = o;
  }
}

// row-permuted f32->bf16: permuted row rp = w*64 + q*16 + j  <-  src row q*512 + w*16 + j
__global__ __launch_bounds__(128) void k_cvt_perm(const float* __restrict__ s,
                                                  unsigned short* __restrict__ d) {
  int rp = blockIdx.x;
  int w = rp >> 6, q = (rp >> 4) & 3, j = rp & 15;
  int rs = q * 512 + w * 16 + j;
  float4 v = ((const float4*)(s + (size_t)rs * 512))[threadIdx.x];
  ushort4 o;
  o.x = f2b(v.x); o.y = f2b(v.y); o.z = f2b(v.z); o.w = f2b(v.w);
  ((ushort4*)(d + (size_t)rp * 512))[threadIdx.x] = o;
}

__global__ __launch_bounds__(256) void k_bias_perm(const float* __restrict__ a,
                                                   const float* __restrict__ b,
                                                   float* __restrict__ o) {
  int rp = blockIdx.x * 256 + threadIdx.x;
  if (rp < 2048) {
    int w = rp >> 6, q = (rp >> 4) & 3, j = rp & 15;
    int rs = q * 512 + w * 16 + j;
    o[rp] = a[rs] + b[rs];
  }
}

// row m = t*16+b  <-  emb[xs[b][t]]  (bf16)
__global__ __launch_bounds__(128) void k_emb_gather(const int* __restrict__ xs,
                                                    const float* __restrict__ emb,
                                                    unsigned short* __restrict__ out) {
  int m = blockIdx.x;
  int tok = xs[(m & 15) * 128 + (m >> 4)];
  float4 v = ((const float4*)(emb + (size_t)tok * 512))[threadIdx.x];
  ushort4 o;
  o.x = f2b(v.x); o.y = f2b(v.y); o.z = f2b(v.z); o.w = f2b(v.w);
  ((ushort4*)(out + (size_t)m * 512))[threadIdx.x] = o;
}

// ---------------- bf16 GEMM, B^T layout (m97-style) ----------------
__global__ __launch_bounds__(256) void k_gemm_bt(const unsigned short* __restrict__ A,
                                                 const unsigned short* __restrict__ Bt,
                                                 const float* __restrict__ bias,
                                                 float* __restrict__ C,
                                                 int M, int N, int K) {
  __shared__ unsigned short As[128 * 32];
  __shared__ unsigned short Bs[128 * 32];
  const int tiles_n = N >> 7;
  const int tm = blockIdx.x / tiles_n;
  const int tn = blockIdx.x % tiles_n;
  const int m0 = tm << 7, n0 = tn << 7;
  const int tid = threadIdx.x;
  const int wave = tid >> 6, lane = tid & 63;
  const int wr = wave >> 1, wc = wave & 1;
  f32x4 acc[4][4] = {};

  const int lo = wave * 2048 + lane * 16;
  for (int k0 = 0; k0 < K; k0 += 32) {
#pragma unroll
    for (int i = 0; i < 2; ++i) {
      int o = lo + i * 1024;
      int row = o >> 6, kb = o & 63;
      __builtin_amdgcn_global_load_lds(
          (const AS1 uint32_t*)((const char*)A + ((size_t)(m0 + row) * K + k0) * 2 + kb),
          (AS3 uint32_t*)((char*)As + wave * 2048 + i * 1024), 16, 0, 0);
    }
#pragma unroll
    for (int i = 0; i < 2; ++i) {
      int o = lo + i * 1024;
      int row = o >> 6, kb = o & 63;
      __builtin_amdgcn_global_load_lds(
          (const AS1 uint32_t*)((const char*)Bt + ((size_t)(n0 + row) * K + k0) * 2 + kb),
          (AS3 uint32_t*)((char*)Bs + wave * 2048 + i * 1024), 16, 0, 0);
    }
    __syncthreads();
    bf16x8 af[4], bfr[4];
    const int lrow = lane & 15;
    const int kb16 = (lane >> 4) * 16;
#pragma unroll
    for (int i = 0; i < 4; ++i)
      af[i] = *(const bf16x8*)((const char*)As + (wr * 64 + i * 16 + lrow) * 64 + kb16);
#pragma unroll
    for (int j = 0; j < 4; ++j)
      bfr[j] = *(const bf16x8*)((const char*)Bs + (wc * 64 + j * 16 + lrow) * 64 + kb16);
#pragma unroll
    for (int i = 0; i < 4; ++i)
#pragma unroll
      for (int j = 0; j < 4; ++j)
        acc[i][j] = __builtin_amdgcn_mfma_f32_16x16x32_bf16(af[i], bfr[j], acc[i][j], 0, 0, 0);
    __syncthreads();
  }
#pragma unroll
  for (int j = 0; j < 4; ++j) {
    int col = n0 + wc * 64 + j * 16 + (lane & 15);
    float bv = bias[col];
#pragma unroll
    for (int i = 0; i < 4; ++i) {
      int r0 = m0 + wr * 64 + i * 16 + (lane >> 4) * 4;
#pragma unroll
      for (int r = 0; r < 4; ++r)
        C[(size_t)(r0 + r) * N + col] = acc[i][j][r] + bv;
    }
  }
}

// ---------------- MFMA LSTM: 32 WGs x 1 wave, W in VGPRs, h via IF$ ----------------
// hsb: [129][16][512] bf16. slot 0 = enc_h; step t reads slot t, writes t+1.
// Slots 1..128 pre-filled with 0xFFFF (bf16 NaN sentinel; h=o*tanh(c) is finite).
// gp/wp/bias columns/rows permuted: rp = w*64 + q*16 + j <-> q*512 + w*16 + j,
// so WG w's 4 MFMA n-tiles are gates q=0..3 for h-cols w*16..w*16+15, and each
// lane ends up holding i,f,g,o for (4 batches x 1 col) -> in-lane gate math,
// f32 c-state never leaves the register.

__global__ __launch_bounds__(64, 1) void k_lstm(const float* __restrict__ gp,
                                                const unsigned short* __restrict__ wp,
                                                const float* __restrict__ encc,
                                                unsigned short* __restrict__ hsb) {
  const int wg = blockIdx.x;   // 0..31
  const int l = threadIdx.x;   // 0..63
  const int lr = l & 15;       // n-col within tile / A batch row
  const int lk = l >> 4;       // k-slice quarter (16B)
  const int col = wg * 16 + lr;

  // W_hh fragments, resident in VGPRs for the whole kernel (64 x 16B = 1KB/lane)
  bf16x8 bfr[4][16];
#pragma unroll
  for (int j = 0; j < 4; ++j)
#pragma unroll
    for (int ks = 0; ks < 16; ++ks)
      bfr[j][ks] = *(const bf16x8*)((const char*)wp +
          (size_t)(wg * 64 + j * 16 + lr) * 1024 + ks * 64 + lk * 16);

  // c-state: 4 batches (lk*4+r) x col, f32, in-lane
  float cst[4];
#pragma unroll
  for (int r = 0; r < 4; ++r) cst[r] = encc[(lk * 4 + r) * 512 + col];

  const uint64_t K1 = 0x0001000100010001ull;
  const uint64_t K8 = 0x8000800080008000ull;
  const int u64off = lr * 128 + lk * 2;  // lane's base u64 index within a slot

  for (int t = 0; t < 128; ++t) {
    // acc init = permuted pre-gates (issued before poll; latency overlaps)
    f32x4 acc[4];
#pragma unroll
    for (int j = 0; j < 4; ++j)
#pragma unroll
      for (int r = 0; r < 4; ++r)
        acc[j][r] = gp[(size_t)(t * 16 + lk * 4 + r) * 2048 + wg * 64 + j * 16 + lr];

    // poll h_{t-1}: A-fragments, sentinel-validated, relaxed agent scope
    union AF { uint64_t q[2]; bf16x8 v; } af[16];
    uint64_t* hb = (uint64_t*)(hsb + (size_t)t * 8192);
    int guard = 0;
    for (;;) {
      uint64_t bad = 0;
#pragma unroll
      for (int ks = 0; ks < 16; ++ks) {
        af[ks].q[0] = __hip_atomic_load(hb + u64off + ks * 8, __ATOMIC_RELAXED,
                                        __HIP_MEMORY_SCOPE_AGENT);
        af[ks].q[1] = __hip_atomic_load(hb + u64off + ks * 8 + 1, __ATOMIC_RELAXED,
                                        __HIP_MEMORY_SCOPE_AGENT);
      }
#pragma unroll
      for (int ks = 0; ks < 16; ++ks) {
        bad |= (~af[ks].q[0] - K1) & af[ks].q[0] & K8;
        bad |= (~af[ks].q[1] - K1) & af[ks].q[1] & K8;
      }
      if (bad == 0) break;
      __builtin_amdgcn_s_sleep(1);
      if (++guard > (1 << 20)) break;  // tripwire: wrong, not hung
    }

    // gates = h @ W^T + pre
#pragma unroll
    for (int j = 0; j < 4; ++j)
#pragma unroll
      for (int ks = 0; ks < 16; ++ks)
        acc[j] = __builtin_amdgcn_mfma_f32_16x16x32_bf16(af[ks].v, bfr[j][ks],
                                                         acc[j], 0, 0, 0);

    // in-lane LSTM cell for 4 (batch, col) pairs; pack col pairs -> u32 store
    unsigned short* hout = hsb + (size_t)(t + 1) * 8192;
#pragma unroll
    for (int r = 0; r < 4; ++r) {
      float iv = fsig(acc[0][r]);
      float fv = fsig(acc[1][r]);
      float gv = ftanh(acc[2][r]);
      float ov = fsig(acc[3][r]);
      cst[r] = fv * cst[r] + iv * gv;
      float hv = ov * ftanh(cst[r]);
      uint32_t mine = f2b(hv);
      uint32_t other = (uint32_t)__shfl_xor((int)mine, 1);
      if ((lr & 1) == 0) {
        uint32_t pk = mine | (other << 16);
        __hip_atomic_store((uint32_t*)(hout + (lk * 4 + r) * 512 + col), pk,
                           __ATOMIC_RELAXED, __HIP_MEMORY_SCOPE_AGENT);
      }
    }
  }
}

// ---------------- launch ----------------

extern "C" void kernel_launch(void* const* d_in, const int* in_sizes, int n_in,
                              void* d_out, int out_size, void* d_ws, size_t ws_size,
                              hipStream_t stream) {
  (void)in_sizes; (void)n_in; (void)out_size; (void)ws_size;
  const int* xs = (const int*)d_in[0];
  const float* ench = (const float*)d_in[2];
  const float* encc = (const float*)d_in[3];
  const float* emb  = (const float*)d_in[4];
  const float* Wih  = (const float*)d_in[5];
  const float* Whh  = (const float*)d_in[6];
  const float* bih  = (const float*)d_in[7];
  const float* bhh  = (const float*)d_in[8];
  const float* Wout = (const float*)d_in[9];
  const float* bout = (const float*)d_in[10];
  float* out = (float*)d_out;

  char* ws = (char*)d_ws;
  size_t off = 0;
  auto take = [&](size_t bytes) {
    char* p = ws + off;
    off += (bytes + 255) & ~(size_t)255;
    return p;
  };
  float* gates_pre      = (float*)take(2048ull * 2048 * 4);        // [T*B][4H] permuted cols
  unsigned short* hsb   = (unsigned short*)take(129ull * 16 * 512 * 2);  // h states bf16
  unsigned short* aemb  = (unsigned short*)take(2048ull * 512 * 2);
  unsigned short* wih_b = (unsigned short*)take(2048ull * 512 * 2);      // permuted rows
  unsigned short* wp_b  = (unsigned short*)take(2048ull * 512 * 2);      // permuted W_hh
  unsigned short* wout_b= (unsigned short*)take(32000ull * 512 * 2);
  float* bias1          = (float*)take(2048 * 4);                        // permuted

  k_cvt_perm<<<2048, 128, 0, stream>>>(Wih, wih_b);
  k_cvt_perm<<<2048, 128, 0, stream>>>(Whh, wp_b);
  k_cvt_bf16<<<2048, 256, 0, stream>>>(Wout, wout_b, 32000 * 512 / 4);
  k_emb_gather<<<2048, 128, 0, stream>>>(xs, emb, aemb);
  k_bias_perm<<<8, 256, 0, stream>>>(bih, bhh, bias1);

  // slot 0 = enc_h (bf16); slots 1..128 = sentinel
  k_cvt_bf16<<<2, 256, 0, stream>>>(ench, hsb, 16 * 512 / 4);
  hipMemsetAsync(hsb + 16 * 512, 0xFF, 128ull * 16 * 512 * 2, stream);

  // gates_pre = aemb @ W_ih_perm^T + (b_ih + b_hh)_perm
  k_gemm_bt<<<256, 256, 0, stream>>>(aemb, wih_b, bias1, gates_pre, 2048, 2048, 512);

  k_lstm<<<32, 64, 0, stream>>>(gates_pre, wp_b, encc, hsb);

  // logits = hs @ W_out^T + b_out   (A = slots 1..128)
  k_gemm_bt<<<4000, 256, 0, stream>>>(hsb + 16 * 512, wout_b, bout, out, 2048, 32000, 512);
}